// Round 6
// baseline (909.393 us; speedup 1.0000x reference)
//
#include <hip/hip_runtime.h>
#include <cstddef>

// Problem constants (static per reference)
#define B_ 2
#define Q_ 300
#define T_ 25
#define C_ 256
#define NH_ 8
#define NL_ 4
#define NP_ 4
#define HD_ 32
#define DFF_ 1024
#define LQ_ (Q_ * T_)           // 7500
#define NTOK_ (B_ * LQ_)        // 15000
#define S_ 21760                // sum of level sizes
#define BS_ (B_ * S_)           // 43520

typedef __bf16 bf16x8 __attribute__((ext_vector_type(8)));
typedef float floatx4 __attribute__((ext_vector_type(4)));
typedef unsigned short ushort_t;

// round-half-up bf16 pack: lo16 = bf16(x), hi16 = bf16(y). Folds to v_perm.
__device__ __forceinline__ unsigned pack_bf16(float x, float y) {
    unsigned ux = __float_as_uint(x) + 0x8000u;
    unsigned uy = __float_as_uint(y) + 0x8000u;
    return (ux >> 16) | (uy & 0xFFFF0000u);
}
__device__ __forceinline__ ushort_t f2bf_s(float x) {
    return (ushort_t)((__float_as_uint(x) + 0x8000u) >> 16);
}
__device__ __forceinline__ float bf2f(ushort_t u) {
    return __uint_as_float((unsigned)u << 16);
}

// ---------------- bf16-MFMA GEMM, templated; 2-deep register prefetch; dual-W; split-K ----
// C[M,N] = act(A[M,K] @ W[N,K]^T + bias[N]); W rows >= N1 come from W2/bias2.
// AMODE: 0 = A fp32; 1 = A fp32 + A2 fp32 (elementwise sum); 2 = A bf16.
// OUT_BF16: C stored bf16 (no split-K) vs fp32 (split-K partial z -> C + z*partStride).
#define GBM 128
#define GBN 128
#define GBK 32
#define LDA_S 40   // LDS row stride in bf16 (pad 32 -> 40 to break bank stride)

template<int AMODE, int OUT_BF16>
__global__ __launch_bounds__(256) void gemm_t(
    const void* __restrict__ Av, const float* __restrict__ A2,
    const float* __restrict__ W, const float* __restrict__ W2, int N1,
    const float* __restrict__ bias, const float* __restrict__ bias2,
    void* __restrict__ Cv, long long partStride,
    int M, int N, int K, int kChunk, int ldc, int relu)
{
    __shared__ unsigned short Asl[GBM * LDA_S];
    __shared__ unsigned short Bsl[GBN * LDA_S];

    const int m0 = blockIdx.x * GBM;
    const int n0 = blockIdx.y * GBN;
    const int z  = blockIdx.z;
    const int kbeg = z * kChunk;
    const int kend = min(K, kbeg + kChunk);

    const int t  = threadIdx.x;
    const int wid  = t >> 6;
    const int lane = t & 63;
    const int wm = (wid >> 1) * 64;    // wave tile origin in M
    const int wn = (wid & 1) * 64;     // wave tile origin in N
    const int fm = lane & 15;          // fragment row
    const int fq = (lane >> 4) * 8;    // fragment k-offset

    floatx4 acc[4][4];
    #pragma unroll
    for (int i = 0; i < 4; ++i)
        #pragma unroll
        for (int j = 0; j < 4; ++j)
            acc[i][j] = (floatx4){0.f, 0.f, 0.f, 0.f};

    float4 pa[2][4];   // fp32-A prefetch (AMODE 0/1)
    uint2  pab[2][4];  // bf16-A prefetch (AMODE 2)
    float4 pw[2][4];
    const float* Af = (const float*)Av;
    const ushort_t* Ab = (const ushort_t*)Av;

    auto load_tiles = [&](int buf, int k0) {
        #pragma unroll
        for (int i = 0; i < 4; ++i) {
            int idx = t + 256 * i;
            int row = idx >> 3;
            int c4  = (idx & 7) * 4;
            int gm = m0 + row;
            if constexpr (AMODE == 2) {
                uint2 v = {0u, 0u};
                if (gm < M) v = *(const uint2*)(Ab + (size_t)gm * K + k0 + c4);
                pab[buf][i] = v;
            } else {
                float4 v = make_float4(0.f, 0.f, 0.f, 0.f);
                if (gm < M) {
                    v = *(const float4*)(Af + (size_t)gm * K + k0 + c4);
                    if constexpr (AMODE == 1) {
                        float4 v2 = *(const float4*)(A2 + (size_t)gm * K + k0 + c4);
                        v.x += v2.x; v.y += v2.y; v.z += v2.z; v.w += v2.w;
                    }
                }
                pa[buf][i] = v;
            }
            int gn = n0 + row;
            const float* wr;
            if (W2 && gn >= N1) wr = W2 + (size_t)(gn - N1) * K;
            else                wr = W + (size_t)gn * K;
            pw[buf][i] = *(const float4*)(wr + k0 + c4);
        }
    };

    load_tiles(0, kbeg);
    if (kbeg + GBK < kend) load_tiles(1, kbeg + GBK);

    for (int k0 = kbeg; k0 < kend; k0 += GBK) {
        const int buf = ((k0 - kbeg) >> 5) & 1;
        // commit prefetched tile to LDS (waits only this buffer's loads)
        #pragma unroll
        for (int i = 0; i < 4; ++i) {
            int idx = t + 256 * i;
            int row = idx >> 3;
            int c4  = (idx & 7) * 4;
            if constexpr (AMODE == 2) {
                *(uint2*)&Asl[row * LDA_S + c4] = pab[buf][i];
            } else {
                uint2 p;
                p.x = pack_bf16(pa[buf][i].x, pa[buf][i].y);
                p.y = pack_bf16(pa[buf][i].z, pa[buf][i].w);
                *(uint2*)&Asl[row * LDA_S + c4] = p;
            }
            uint2 q;
            q.x = pack_bf16(pw[buf][i].x, pw[buf][i].y);
            q.y = pack_bf16(pw[buf][i].z, pw[buf][i].w);
            *(uint2*)&Bsl[row * LDA_S + c4] = q;
        }
        __syncthreads();

        // refill this buffer two tiles ahead; stays in flight through the MFMAs
        if (k0 + 2 * GBK < kend) load_tiles(buf, k0 + 2 * GBK);

        bf16x8 af[4], bfr[4];
        #pragma unroll
        for (int i = 0; i < 4; ++i)
            af[i] = *(const bf16x8*)&Asl[(wm + i * 16 + fm) * LDA_S + fq];
        #pragma unroll
        for (int j = 0; j < 4; ++j)
            bfr[j] = *(const bf16x8*)&Bsl[(wn + j * 16 + fm) * LDA_S + fq];

        #pragma unroll
        for (int i = 0; i < 4; ++i)
            #pragma unroll
            for (int j = 0; j < 4; ++j)
                acc[i][j] = __builtin_amdgcn_mfma_f32_16x16x32_bf16(af[i], bfr[j], acc[i][j], 0, 0, 0);
        __syncthreads();
    }

    // epilogue: C/D layout col=lane&15, row=(lane>>4)*4+reg
    float* Cf = (float*)Cv + (long long)z * partStride;
    ushort_t* Cb = (ushort_t*)Cv;
    const int cr = (lane >> 4) * 4;
    const int cc = lane & 15;
    #pragma unroll
    for (int j = 0; j < 4; ++j) {
        int gn = n0 + wn + j * 16 + cc;
        float bia = 0.f;
        if (z == 0) bia = (bias2 && gn >= N1) ? bias2[gn - N1] : bias[gn];
        #pragma unroll
        for (int i = 0; i < 4; ++i) {
            #pragma unroll
            for (int r = 0; r < 4; ++r) {
                int gm = m0 + wm + i * 16 + cr + r;
                if (gm < M) {
                    float v = acc[i][j][r] + bia;
                    if (relu) v = fmaxf(v, 0.f);
                    if constexpr (OUT_BF16) Cb[(size_t)gm * ldc + gn] = f2bf_s(v);
                    else                    Cf[(size_t)gm * ldc + gn] = v;
                }
            }
        }
    }
}

// ---------------- self-attention over T=25, one wave per (seq, head); bf16 in/out ----------------
__global__ __launch_bounds__(64) void attn_kernel(
    const ushort_t* __restrict__ qkv,   // [NTOK, 768] bf16: q|k|v per token
    ushort_t* __restrict__ o)           // [NTOK, 256] bf16
{
    int sh = blockIdx.x;
    int s = sh >> 3, h = sh & 7;     // s in [0, 600), h in [0, 8)
    __shared__ float qs[T_][HD_], ks[T_][HD_], vs[T_][HD_];
    int t = threadIdx.x;

    for (int idx = t; idx < T_ * HD_; idx += 64) {
        int i = idx >> 5, d = idx & 31;
        size_t base = ((size_t)(s * T_ + i)) * 768 + h * HD_ + d;
        qs[i][d] = bf2f(qkv[base]);
        ks[i][d] = bf2f(qkv[base + 256]);
        vs[i][d] = bf2f(qkv[base + 512]);
    }
    __syncthreads();

    if (t < T_) {
        float sc[T_];
        float mx = -1e30f;
        #pragma unroll
        for (int j = 0; j < T_; ++j) {
            float dot = 0.f;
            #pragma unroll
            for (int d = 0; d < HD_; ++d) dot += qs[t][d] * ks[j][d];
            sc[j] = dot * 0.17677669529663687f;  // 1/sqrt(32)
            mx = fmaxf(mx, sc[j]);
        }
        float sum = 0.f;
        #pragma unroll
        for (int j = 0; j < T_; ++j) { sc[j] = __expf(sc[j] - mx); sum += sc[j]; }
        float inv = 1.f / sum;
        float out[HD_];
        #pragma unroll
        for (int d = 0; d < HD_; ++d) out[d] = 0.f;
        for (int j = 0; j < T_; ++j) {
            float p = sc[j] * inv;
            #pragma unroll
            for (int d = 0; d < HD_; ++d) out[d] += p * vs[j][d];
        }
        size_t ob = ((size_t)(s * T_ + t)) * C_ + h * HD_;
        #pragma unroll
        for (int d = 0; d < HD_; ++d) o[ob + d] = f2bf_s(out[d]);
    }
}

// ---------------- fused residual + LayerNorm; r = sum of nparts fp32 partials ----------------
__global__ __launch_bounds__(256) void ln_kernel(
    const float* __restrict__ x, const float* __restrict__ r,
    int nparts, long long rstride,
    const float* __restrict__ g, const float* __restrict__ b,
    float* __restrict__ out, const float* __restrict__ pos,
    float* __restrict__ qout)
{
    int tok = blockIdx.x;
    int t = threadIdx.x;
    size_t base = (size_t)tok * C_;
    float v = x[base + t];
    for (int p = 0; p < nparts; ++p)
        v += r[(long long)base + t + (long long)p * rstride];

    float s = v, ss = v * v;
    #pragma unroll
    for (int off = 32; off; off >>= 1) {
        s += __shfl_down(s, off);
        ss += __shfl_down(ss, off);
    }
    __shared__ float ws[4], wss[4];
    __shared__ float mean_s, rstd_s;
    int wid = t >> 6, lane = t & 63;
    if (lane == 0) { ws[wid] = s; wss[wid] = ss; }
    __syncthreads();
    if (t == 0) {
        float S = 0.f, SS = 0.f;
        #pragma unroll
        for (int i = 0; i < 4; ++i) { S += ws[i]; SS += wss[i]; }
        float m = S / 256.f;
        float var = SS / 256.f - m * m;
        mean_s = m;
        rstd_s = rsqrtf(var + 1e-5f);
    }
    __syncthreads();
    float y = (v - mean_s) * rstd_s * g[t] + b[t];
    out[base + t] = y;
    if (qout) qout[base + t] = y + pos[base + t];
}

// ---------------- deformable sampling: one wave per token, 8 lanes per head; bf16 value ----------
__global__ __launch_bounds__(256) void deform_kernel(
    const ushort_t* __restrict__ value,   // [B, S, NH, HD] bf16
    const float* __restrict__ d12,        // [NTOK, 384] = offsets | aw logits
    const float* __restrict__ refpts,     // [B, LQ, NL, 2]
    ushort_t* __restrict__ out)           // [NTOK, 256] bf16, laid out (tok, h, d)
{
    const int tok = (blockIdx.x * 256 + threadIdx.x) >> 6;   // one wave per token
    const int lane = threadIdx.x & 63;
    const int h  = lane >> 3;          // head 0..7
    const int d4 = (lane & 7) * 4;     // channel offset 0,4,...,28
    const int b = tok / LQ_;

    const float* awp = d12 + (size_t)tok * 384 + 256 + h * 16;
    float logit[16];
    float mx = -1e30f;
    #pragma unroll
    for (int i = 0; i < 16; ++i) { logit[i] = awp[i]; mx = fmaxf(mx, logit[i]); }
    float sum = 0.f;
    #pragma unroll
    for (int i = 0; i < 16; ++i) { logit[i] = __expf(logit[i] - mx); sum += logit[i]; }
    float inv = 1.f / sum;

    const float* offp = d12 + (size_t)tok * 384 + h * 32;
    const float* refp = refpts + (size_t)tok * (NL_ * 2);

    const int HW[4]     = {128, 64, 32, 16};
    const int starts[4] = {0, 16384, 20480, 21504};

    floatx4 acc = (floatx4){0.f, 0.f, 0.f, 0.f};
    #pragma unroll
    for (int l = 0; l < 4; ++l) {
        const int Hl = HW[l], Wl = HW[l];
        float rx = refp[l * 2 + 0], ry = refp[l * 2 + 1];
        const ushort_t* vbase = value + ((size_t)b * S_ + starts[l]) * (NH_ * HD_) + h * HD_ + d4;
        #pragma unroll
        for (int p = 0; p < 4; ++p) {
            float ox = offp[(l * 4 + p) * 2 + 0];
            float oy = offp[(l * 4 + p) * 2 + 1];
            float xl = rx * (float)Wl + ox - 0.5f;
            float yl = ry * (float)Hl + oy - 0.5f;
            float x0f = floorf(xl), y0f = floorf(yl);
            int x0 = (int)x0f, y0 = (int)y0f;
            float wx1 = xl - x0f, wy1 = yl - y0f;
            float wx0 = 1.f - wx1, wy0 = 1.f - wy1;
            float aww = logit[l * 4 + p] * inv;

            floatx4 sv = (floatx4){0.f, 0.f, 0.f, 0.f};
            #pragma unroll
            for (int c = 0; c < 4; ++c) {
                int dx = c & 1, dy = c >> 1;
                int xi = x0 + dx, yi = y0 + dy;
                float w = (dx ? wx1 : wx0) * (dy ? wy1 : wy0);
                bool valid = (xi >= 0) & (xi < Wl) & (yi >= 0) & (yi < Hl);
                int xc = min(max(xi, 0), Wl - 1);
                int yc = min(max(yi, 0), Hl - 1);
                uint2 raw = *(const uint2*)(vbase + ((size_t)(yc * Wl + xc)) * (NH_ * HD_));
                float wv = valid ? w : 0.f;
                sv[0] += __uint_as_float((raw.x & 0xFFFFu) << 16) * wv;
                sv[1] += __uint_as_float(raw.x & 0xFFFF0000u) * wv;
                sv[2] += __uint_as_float((raw.y & 0xFFFFu) << 16) * wv;
                sv[3] += __uint_as_float(raw.y & 0xFFFF0000u) * wv;
            }
            acc += sv * aww;
        }
    }
    uint2 po;
    po.x = pack_bf16(acc[0], acc[1]);
    po.y = pack_bf16(acc[2], acc[3]);
    *(uint2*)(out + (size_t)tok * C_ + lane * 4) = po;
}

// ---------------- host launch ----------------
extern "C" void kernel_launch(void* const* d_in, const int* in_sizes, int n_in,
                              void* d_out, int out_size, void* d_ws, size_t ws_size,
                              hipStream_t stream) {
    const float* tgt_text = (const float*)d_in[0];
    const float* pos      = (const float*)d_in[1];
    const float* refpts   = (const float*)d_in[2];
    const float* src      = (const float*)d_in[3];
    // d_in[4], d_in[5]: spatial shapes / level starts (static, unused)
    const float* in_proj_w  = (const float*)d_in[6];
    const float* in_proj_b  = (const float*)d_in[7];
    const float* out_proj_w = (const float*)d_in[8];
    const float* out_proj_b = (const float*)d_in[9];
    const float* ln1_g = (const float*)d_in[10];
    const float* ln1_b = (const float*)d_in[11];
    const float* samp_off_w = (const float*)d_in[12];
    const float* samp_off_b = (const float*)d_in[13];
    const float* aw_w = (const float*)d_in[14];
    const float* aw_b = (const float*)d_in[15];
    const float* vp_w = (const float*)d_in[16];
    const float* vp_b = (const float*)d_in[17];
    const float* op_w = (const float*)d_in[18];
    const float* op_b = (const float*)d_in[19];
    const float* ln2_g = (const float*)d_in[20];
    const float* ln2_b = (const float*)d_in[21];
    const float* ffn1_w = (const float*)d_in[22];
    const float* ffn1_b = (const float*)d_in[23];
    const float* ffn2_w = (const float*)d_in[24];
    const float* ffn2_b = (const float*)d_in[25];
    const float* ln3_g = (const float*)d_in[26];
    const float* ln3_b = (const float*)d_in[27];

    const long long NC = (long long)NTOK_ * C_;    // 3,840,000 floats
    float* ws = (float*)d_ws;
    float* A    = ws;                               // [NTOK,C] fp32  tgt (post-LN1/LN2)
    float* Bq   = ws + NC;                          // [NTOK,C] fp32  query; later partial
    float* Creg = ws + 2 * NC;                      // region: qkv/value/ffn-hidden (bf16)
    float* D12  = Creg + (long long)NTOK_ * DFF_;   // [NTOK,384] fp32; also partial scratch
    float* E    = D12 + (long long)NTOK_ * 384;     // [NTOK,C]: bf16 attn/deform out; fp32 partial
    float* F    = E + NC;                           // [NTOK,C] fp32 partial accumulator
    const long long wsEnd = (long long)(F - ws) + NC;   // 36.48M floats

    // FFN2 split-K: 4 if workspace has room for 2 extra NC partials past F, else 2
    const int zparts = (ws_size >= (size_t)(wsEnd + 2 * NC) * sizeof(float)) ? 4 : 2;

    const int MB  = (NTOK_ + GBM - 1) / GBM;   // 118
    const int MBV = BS_ / GBM;                 // 340

    // 1. QK projection on (tgt+pos) -> qkv bf16 cols 0..511; V projection on tgt -> cols 512..767
    gemm_t<1, 1><<<dim3(MB, 4, 1), 256, 0, stream>>>(tgt_text, pos, in_proj_w, nullptr, 0,
        in_proj_b, nullptr, Creg, 0, NTOK_, 512, 256, 256, 768, 0);
    gemm_t<0, 1><<<dim3(MB, 2, 1), 256, 0, stream>>>(tgt_text, nullptr, in_proj_w + 512 * 256, nullptr, 0,
        in_proj_b + 512, nullptr, (void*)((ushort_t*)Creg + 512), 0, NTOK_, 256, 256, 256, 768, 0);
    // 2. self-attention (bf16 -> bf16)
    attn_kernel<<<B_ * Q_ * NH_, 64, 0, stream>>>((const ushort_t*)Creg, (ushort_t*)E);
    // 3. out projection (A bf16), split-K x2: partial0=F, partial1=D12 (dead until step 6)
    gemm_t<2, 0><<<dim3(MB, 2, 2), 256, 0, stream>>>(E, nullptr, out_proj_w, nullptr, 0,
        out_proj_b, nullptr, F, (long long)(D12 - F), NTOK_, 256, 256, 128, 256, 0);
    // 4. LN1 (+ residual over 2 partials), and query = tgt + pos
    ln_kernel<<<NTOK_, 256, 0, stream>>>(tgt_text, F, 2, (long long)(D12 - F),
                                         ln1_g, ln1_b, A, pos, Bq);
    // 5. value projection -> bf16 [BS,256]
    gemm_t<0, 1><<<dim3(MBV, 2, 1), 256, 0, stream>>>(src, nullptr, vp_w, nullptr, 0,
        vp_b, nullptr, Creg, 0, BS_, 256, 256, 256, 256, 0);
    // 6. sampling offsets + aw logits, merged (N=384, dual weights) -> fp32 D12
    gemm_t<0, 0><<<dim3(MB, 3, 1), 256, 0, stream>>>(Bq, nullptr, samp_off_w, aw_w, 256,
        samp_off_b, aw_b, D12, 0, NTOK_, 384, 256, 256, 384, 0);
    // 7. deformable sampling (bf16 value, bf16 out)
    deform_kernel<<<NTOK_ / 4, 256, 0, stream>>>((const ushort_t*)Creg, D12, refpts, (ushort_t*)E);
    // 8. output projection of cross-attn (A bf16), split-K x2: partial0=F, partial1=Bq (dead)
    gemm_t<2, 0><<<dim3(MB, 2, 2), 256, 0, stream>>>(E, nullptr, op_w, nullptr, 0,
        op_b, nullptr, F, (long long)(Bq - F), NTOK_, 256, 256, 128, 256, 0);
    // 9. LN2 (+ residual over 2 partials), in place on A
    ln_kernel<<<NTOK_, 256, 0, stream>>>(A, F, 2, (long long)(Bq - F),
                                         ln2_g, ln2_b, A, nullptr, nullptr);
    // 10. FFN1 + ReLU -> bf16 hidden [NTOK,1024]
    gemm_t<0, 1><<<dim3(MB, 8, 1), 256, 0, stream>>>(A, nullptr, ffn1_w, nullptr, 0,
        ffn1_b, nullptr, Creg, 0, NTOK_, DFF_, 256, 256, DFF_, 1);
    // 11. FFN2 (A bf16), split-K x zparts: partials at E, F, F+NC, F+2NC (stride NC from E)
    gemm_t<2, 0><<<dim3(MB, 2, zparts), 256, 0, stream>>>(Creg, nullptr, ffn2_w, nullptr, 0,
        ffn2_b, nullptr, E, NC, NTOK_, 256, 1024, 1024 / zparts, 256, 0);
    // 12. LN3 (+ residual over zparts partials) -> d_out
    ln_kernel<<<NTOK_, 256, 0, stream>>>(A, E, zparts, NC,
                                         ln3_g, ln3_b, (float*)d_out, nullptr, nullptr);
}

// Round 7
// 498.925 us; speedup vs baseline: 1.8227x; 1.8227x over previous
//
#include <hip/hip_runtime.h>
#include <cstddef>

// Problem constants (static per reference)
#define B_ 2
#define Q_ 300
#define T_ 25
#define C_ 256
#define NH_ 8
#define NL_ 4
#define NP_ 4
#define HD_ 32
#define DFF_ 1024
#define LQ_ (Q_ * T_)           // 7500
#define NTOK_ (B_ * LQ_)        // 15000
#define S_ 21760                // sum of level sizes
#define BS_ (B_ * S_)           // 43520

typedef __bf16 bf16x8 __attribute__((ext_vector_type(8)));
typedef float floatx4 __attribute__((ext_vector_type(4)));
typedef unsigned short ushort_t;

// round-half-up bf16 pack: lo16 = bf16(x), hi16 = bf16(y). Folds to v_perm.
__device__ __forceinline__ unsigned pack_bf16(float x, float y) {
    unsigned ux = __float_as_uint(x) + 0x8000u;
    unsigned uy = __float_as_uint(y) + 0x8000u;
    return (ux >> 16) | (uy & 0xFFFF0000u);
}
__device__ __forceinline__ ushort_t f2bf_s(float x) {
    return (ushort_t)((__float_as_uint(x) + 0x8000u) >> 16);
}
__device__ __forceinline__ float bf2f(ushort_t u) {
    return __uint_as_float((unsigned)u << 16);
}

// ---------------- bf16-MFMA GEMM, templated; 1-deep register prefetch; dual-W; split-K ----
// C[M,N] = act(A[M,K] @ W[N,K]^T + bias[N]); W rows >= N1 come from W2/bias2.
// AMODE: 0 = A fp32; 1 = A fp32 + A2 fp32 (elementwise sum); 2 = A bf16.
// OUT_BF16: C stored bf16 (no split-K) vs fp32 (split-K partial z -> C + z*partStride).
// NOTE: 2-deep prefetch spills to scratch (R6: 265MB scratch writes/dispatch) — keep 1-deep.
#define GBM 128
#define GBN 128
#define GBK 32
#define LDA_S 40   // LDS row stride in bf16 (pad 32 -> 40 to break bank stride)

template<int AMODE, int OUT_BF16>
__global__ __launch_bounds__(256) void gemm_t(
    const void* __restrict__ Av, const float* __restrict__ A2,
    const float* __restrict__ W, const float* __restrict__ W2, int N1,
    const float* __restrict__ bias, const float* __restrict__ bias2,
    void* __restrict__ Cv, long long partStride,
    int M, int N, int K, int kChunk, int ldc, int relu)
{
    __shared__ unsigned short Asl[GBM * LDA_S];
    __shared__ unsigned short Bsl[GBN * LDA_S];

    const int m0 = blockIdx.x * GBM;
    const int n0 = blockIdx.y * GBN;
    const int z  = blockIdx.z;
    const int kbeg = z * kChunk;
    const int kend = min(K, kbeg + kChunk);

    const int t  = threadIdx.x;
    const int wid  = t >> 6;
    const int lane = t & 63;
    const int wm = (wid >> 1) * 64;    // wave tile origin in M
    const int wn = (wid & 1) * 64;     // wave tile origin in N
    const int fm = lane & 15;          // fragment row
    const int fq = (lane >> 4) * 8;    // fragment k-offset

    floatx4 acc[4][4];
    #pragma unroll
    for (int i = 0; i < 4; ++i)
        #pragma unroll
        for (int j = 0; j < 4; ++j)
            acc[i][j] = (floatx4){0.f, 0.f, 0.f, 0.f};

    float4 pa[4];   // fp32-A prefetch (AMODE 0/1)
    uint2  pab[4];  // bf16-A prefetch (AMODE 2)
    float4 pw[4];
    const float* Af = (const float*)Av;
    const ushort_t* Ab = (const ushort_t*)Av;

    auto load_tiles = [&](int k0) {
        #pragma unroll
        for (int i = 0; i < 4; ++i) {
            int idx = t + 256 * i;
            int row = idx >> 3;
            int c4  = (idx & 7) * 4;
            int gm = m0 + row;
            if constexpr (AMODE == 2) {
                uint2 v = {0u, 0u};
                if (gm < M) v = *(const uint2*)(Ab + (size_t)gm * K + k0 + c4);
                pab[i] = v;
            } else {
                float4 v = make_float4(0.f, 0.f, 0.f, 0.f);
                if (gm < M) {
                    v = *(const float4*)(Af + (size_t)gm * K + k0 + c4);
                    if constexpr (AMODE == 1) {
                        float4 v2 = *(const float4*)(A2 + (size_t)gm * K + k0 + c4);
                        v.x += v2.x; v.y += v2.y; v.z += v2.z; v.w += v2.w;
                    }
                }
                pa[i] = v;
            }
            int gn = n0 + row;
            const float* wr;
            if (W2 && gn >= N1) wr = W2 + (size_t)(gn - N1) * K;
            else                wr = W + (size_t)gn * K;
            pw[i] = *(const float4*)(wr + k0 + c4);
        }
    };

    load_tiles(kbeg);
    for (int k0 = kbeg; k0 < kend; k0 += GBK) {
        // commit prefetched tile to LDS
        #pragma unroll
        for (int i = 0; i < 4; ++i) {
            int idx = t + 256 * i;
            int row = idx >> 3;
            int c4  = (idx & 7) * 4;
            if constexpr (AMODE == 2) {
                *(uint2*)&Asl[row * LDA_S + c4] = pab[i];
            } else {
                uint2 p;
                p.x = pack_bf16(pa[i].x, pa[i].y);
                p.y = pack_bf16(pa[i].z, pa[i].w);
                *(uint2*)&Asl[row * LDA_S + c4] = p;
            }
            uint2 q;
            q.x = pack_bf16(pw[i].x, pw[i].y);
            q.y = pack_bf16(pw[i].z, pw[i].w);
            *(uint2*)&Bsl[row * LDA_S + c4] = q;
        }
        __syncthreads();

        // issue next tile's global loads; they complete during the MFMAs below
        if (k0 + GBK < kend) load_tiles(k0 + GBK);

        bf16x8 af[4], bfr[4];
        #pragma unroll
        for (int i = 0; i < 4; ++i)
            af[i] = *(const bf16x8*)&Asl[(wm + i * 16 + fm) * LDA_S + fq];
        #pragma unroll
        for (int j = 0; j < 4; ++j)
            bfr[j] = *(const bf16x8*)&Bsl[(wn + j * 16 + fm) * LDA_S + fq];

        #pragma unroll
        for (int i = 0; i < 4; ++i)
            #pragma unroll
            for (int j = 0; j < 4; ++j)
                acc[i][j] = __builtin_amdgcn_mfma_f32_16x16x32_bf16(af[i], bfr[j], acc[i][j], 0, 0, 0);
        __syncthreads();
    }

    // epilogue: C/D layout col=lane&15, row=(lane>>4)*4+reg
    float* Cf = (float*)Cv + (long long)z * partStride;
    ushort_t* Cb = (ushort_t*)Cv;
    const int cr = (lane >> 4) * 4;
    const int cc = lane & 15;
    #pragma unroll
    for (int j = 0; j < 4; ++j) {
        int gn = n0 + wn + j * 16 + cc;
        float bia = 0.f;
        if (z == 0) bia = (bias2 && gn >= N1) ? bias2[gn - N1] : bias[gn];
        #pragma unroll
        for (int i = 0; i < 4; ++i) {
            #pragma unroll
            for (int r = 0; r < 4; ++r) {
                int gm = m0 + wm + i * 16 + cr + r;
                if (gm < M) {
                    float v = acc[i][j][r] + bia;
                    if (relu) v = fmaxf(v, 0.f);
                    if constexpr (OUT_BF16) Cb[(size_t)gm * ldc + gn] = f2bf_s(v);
                    else                    Cf[(size_t)gm * ldc + gn] = v;
                }
            }
        }
    }
}

// ---------------- self-attention over T=25, one wave per (seq, head); bf16 in/out ----------------
__global__ __launch_bounds__(64) void attn_kernel(
    const ushort_t* __restrict__ qkv,   // [NTOK, 768] bf16: q|k|v per token
    ushort_t* __restrict__ o)           // [NTOK, 256] bf16
{
    int sh = blockIdx.x;
    int s = sh >> 3, h = sh & 7;     // s in [0, 600), h in [0, 8)
    __shared__ float qs[T_][HD_], ks[T_][HD_], vs[T_][HD_];
    int t = threadIdx.x;

    for (int idx = t; idx < T_ * HD_; idx += 64) {
        int i = idx >> 5, d = idx & 31;
        size_t base = ((size_t)(s * T_ + i)) * 768 + h * HD_ + d;
        qs[i][d] = bf2f(qkv[base]);
        ks[i][d] = bf2f(qkv[base + 256]);
        vs[i][d] = bf2f(qkv[base + 512]);
    }
    __syncthreads();

    if (t < T_) {
        float sc[T_];
        float mx = -1e30f;
        #pragma unroll
        for (int j = 0; j < T_; ++j) {
            float dot = 0.f;
            #pragma unroll
            for (int d = 0; d < HD_; ++d) dot += qs[t][d] * ks[j][d];
            sc[j] = dot * 0.17677669529663687f;  // 1/sqrt(32)
            mx = fmaxf(mx, sc[j]);
        }
        float sum = 0.f;
        #pragma unroll
        for (int j = 0; j < T_; ++j) { sc[j] = __expf(sc[j] - mx); sum += sc[j]; }
        float inv = 1.f / sum;
        float out[HD_];
        #pragma unroll
        for (int d = 0; d < HD_; ++d) out[d] = 0.f;
        for (int j = 0; j < T_; ++j) {
            float p = sc[j] * inv;
            #pragma unroll
            for (int d = 0; d < HD_; ++d) out[d] += p * vs[j][d];
        }
        size_t ob = ((size_t)(s * T_ + t)) * C_ + h * HD_;
        #pragma unroll
        for (int d = 0; d < HD_; ++d) o[ob + d] = f2bf_s(out[d]);
    }
}

// ---------------- fused residual + LayerNorm; r = sum of nparts fp32 partials ----------------
__global__ __launch_bounds__(256) void ln_kernel(
    const float* __restrict__ x, const float* __restrict__ r,
    int nparts, long long rstride,
    const float* __restrict__ g, const float* __restrict__ b,
    float* __restrict__ out, const float* __restrict__ pos,
    float* __restrict__ qout)
{
    int tok = blockIdx.x;
    int t = threadIdx.x;
    size_t base = (size_t)tok * C_;
    float v = x[base + t];
    for (int p = 0; p < nparts; ++p)
        v += r[(long long)base + t + (long long)p * rstride];

    float s = v, ss = v * v;
    #pragma unroll
    for (int off = 32; off; off >>= 1) {
        s += __shfl_down(s, off);
        ss += __shfl_down(ss, off);
    }
    __shared__ float ws[4], wss[4];
    __shared__ float mean_s, rstd_s;
    int wid = t >> 6, lane = t & 63;
    if (lane == 0) { ws[wid] = s; wss[wid] = ss; }
    __syncthreads();
    if (t == 0) {
        float S = 0.f, SS = 0.f;
        #pragma unroll
        for (int i = 0; i < 4; ++i) { S += ws[i]; SS += wss[i]; }
        float m = S / 256.f;
        float var = SS / 256.f - m * m;
        mean_s = m;
        rstd_s = rsqrtf(var + 1e-5f);
    }
    __syncthreads();
    float y = (v - mean_s) * rstd_s * g[t] + b[t];
    out[base + t] = y;
    if (qout) qout[base + t] = y + pos[base + t];
}

// ---------------- deformable sampling: one wave per token, 8 lanes per head; bf16 value ----------
__global__ __launch_bounds__(256) void deform_kernel(
    const ushort_t* __restrict__ value,   // [B, S, NH, HD] bf16
    const float* __restrict__ d12,        // [NTOK, 384] = offsets | aw logits
    const float* __restrict__ refpts,     // [B, LQ, NL, 2]
    ushort_t* __restrict__ out)           // [NTOK, 256] bf16, laid out (tok, h, d)
{
    const int tok = (blockIdx.x * 256 + threadIdx.x) >> 6;   // one wave per token
    const int lane = threadIdx.x & 63;
    const int h  = lane >> 3;          // head 0..7
    const int d4 = (lane & 7) * 4;     // channel offset 0,4,...,28
    const int b = tok / LQ_;

    const float* awp = d12 + (size_t)tok * 384 + 256 + h * 16;
    float logit[16];
    float mx = -1e30f;
    #pragma unroll
    for (int i = 0; i < 16; ++i) { logit[i] = awp[i]; mx = fmaxf(mx, logit[i]); }
    float sum = 0.f;
    #pragma unroll
    for (int i = 0; i < 16; ++i) { logit[i] = __expf(logit[i] - mx); sum += logit[i]; }
    float inv = 1.f / sum;

    const float* offp = d12 + (size_t)tok * 384 + h * 32;
    const float* refp = refpts + (size_t)tok * (NL_ * 2);

    const int HW[4]     = {128, 64, 32, 16};
    const int starts[4] = {0, 16384, 20480, 21504};

    floatx4 acc = (floatx4){0.f, 0.f, 0.f, 0.f};
    #pragma unroll
    for (int l = 0; l < 4; ++l) {
        const int Hl = HW[l], Wl = HW[l];
        float rx = refp[l * 2 + 0], ry = refp[l * 2 + 1];
        const ushort_t* vbase = value + ((size_t)b * S_ + starts[l]) * (NH_ * HD_) + h * HD_ + d4;
        #pragma unroll
        for (int p = 0; p < 4; ++p) {
            float ox = offp[(l * 4 + p) * 2 + 0];
            float oy = offp[(l * 4 + p) * 2 + 1];
            float xl = rx * (float)Wl + ox - 0.5f;
            float yl = ry * (float)Hl + oy - 0.5f;
            float x0f = floorf(xl), y0f = floorf(yl);
            int x0 = (int)x0f, y0 = (int)y0f;
            float wx1 = xl - x0f, wy1 = yl - y0f;
            float wx0 = 1.f - wx1, wy0 = 1.f - wy1;
            float aww = logit[l * 4 + p] * inv;

            floatx4 sv = (floatx4){0.f, 0.f, 0.f, 0.f};
            #pragma unroll
            for (int c = 0; c < 4; ++c) {
                int dx = c & 1, dy = c >> 1;
                int xi = x0 + dx, yi = y0 + dy;
                float w = (dx ? wx1 : wx0) * (dy ? wy1 : wy0);
                bool valid = (xi >= 0) & (xi < Wl) & (yi >= 0) & (yi < Hl);
                int xc = min(max(xi, 0), Wl - 1);
                int yc = min(max(yi, 0), Hl - 1);
                uint2 raw = *(const uint2*)(vbase + ((size_t)(yc * Wl + xc)) * (NH_ * HD_));
                float wv = valid ? w : 0.f;
                sv[0] += __uint_as_float((raw.x & 0xFFFFu) << 16) * wv;
                sv[1] += __uint_as_float(raw.x & 0xFFFF0000u) * wv;
                sv[2] += __uint_as_float((raw.y & 0xFFFFu) << 16) * wv;
                sv[3] += __uint_as_float(raw.y & 0xFFFF0000u) * wv;
            }
            acc += sv * aww;
        }
    }
    uint2 po;
    po.x = pack_bf16(acc[0], acc[1]);
    po.y = pack_bf16(acc[2], acc[3]);
    *(uint2*)(out + (size_t)tok * C_ + lane * 4) = po;
}

// ---------------- host launch ----------------
extern "C" void kernel_launch(void* const* d_in, const int* in_sizes, int n_in,
                              void* d_out, int out_size, void* d_ws, size_t ws_size,
                              hipStream_t stream) {
    const float* tgt_text = (const float*)d_in[0];
    const float* pos      = (const float*)d_in[1];
    const float* refpts   = (const float*)d_in[2];
    const float* src      = (const float*)d_in[3];
    // d_in[4], d_in[5]: spatial shapes / level starts (static, unused)
    const float* in_proj_w  = (const float*)d_in[6];
    const float* in_proj_b  = (const float*)d_in[7];
    const float* out_proj_w = (const float*)d_in[8];
    const float* out_proj_b = (const float*)d_in[9];
    const float* ln1_g = (const float*)d_in[10];
    const float* ln1_b = (const float*)d_in[11];
    const float* samp_off_w = (const float*)d_in[12];
    const float* samp_off_b = (const float*)d_in[13];
    const float* aw_w = (const float*)d_in[14];
    const float* aw_b = (const float*)d_in[15];
    const float* vp_w = (const float*)d_in[16];
    const float* vp_b = (const float*)d_in[17];
    const float* op_w = (const float*)d_in[18];
    const float* op_b = (const float*)d_in[19];
    const float* ln2_g = (const float*)d_in[20];
    const float* ln2_b = (const float*)d_in[21];
    const float* ffn1_w = (const float*)d_in[22];
    const float* ffn1_b = (const float*)d_in[23];
    const float* ffn2_w = (const float*)d_in[24];
    const float* ffn2_b = (const float*)d_in[25];
    const float* ln3_g = (const float*)d_in[26];
    const float* ln3_b = (const float*)d_in[27];

    const long long NC = (long long)NTOK_ * C_;    // 3,840,000 floats
    float* ws = (float*)d_ws;
    float* A    = ws;                               // [NTOK,C] fp32  tgt (post-LN1/LN2)
    float* Bq   = ws + NC;                          // [NTOK,C] fp32  query; later partial
    float* Creg = ws + 2 * NC;                      // region: qkv/value/ffn-hidden (bf16)
    float* D12  = Creg + (long long)NTOK_ * DFF_;   // [NTOK,384] fp32; also partial scratch
    float* E    = D12 + (long long)NTOK_ * 384;     // [NTOK,C]: bf16 attn/deform out; fp32 partial
    float* F    = E + NC;                           // [NTOK,C] fp32 partial accumulator
    const long long wsEnd = (long long)(F - ws) + NC;   // floats used so far

    // FFN2 split-K: 4 if workspace has room for 2 extra NC partials past F, else 2
    const int zparts = (ws_size >= (size_t)(wsEnd + 2 * NC) * sizeof(float)) ? 4 : 2;

    const int MB  = (NTOK_ + GBM - 1) / GBM;   // 118
    const int MBV = BS_ / GBM;                 // 340

    // 1. QK projection on (tgt+pos) -> qkv bf16 cols 0..511; V projection on tgt -> cols 512..767
    gemm_t<1, 1><<<dim3(MB, 4, 1), 256, 0, stream>>>(tgt_text, pos, in_proj_w, nullptr, 0,
        in_proj_b, nullptr, Creg, 0, NTOK_, 512, 256, 256, 768, 0);
    gemm_t<0, 1><<<dim3(MB, 2, 1), 256, 0, stream>>>(tgt_text, nullptr, in_proj_w + 512 * 256, nullptr, 0,
        in_proj_b + 512, nullptr, (void*)((ushort_t*)Creg + 512), 0, NTOK_, 256, 256, 256, 768, 0);
    // 2. self-attention (bf16 -> bf16)
    attn_kernel<<<B_ * Q_ * NH_, 64, 0, stream>>>((const ushort_t*)Creg, (ushort_t*)E);
    // 3. out projection (A bf16), split-K x2: partial0=F, partial1=D12 (dead until step 6)
    gemm_t<2, 0><<<dim3(MB, 2, 2), 256, 0, stream>>>(E, nullptr, out_proj_w, nullptr, 0,
        out_proj_b, nullptr, F, (long long)(D12 - F), NTOK_, 256, 256, 128, 256, 0);
    // 4. LN1 (+ residual over 2 partials), and query = tgt + pos
    ln_kernel<<<NTOK_, 256, 0, stream>>>(tgt_text, F, 2, (long long)(D12 - F),
                                         ln1_g, ln1_b, A, pos, Bq);
    // 5. value projection -> bf16 [BS,256]
    gemm_t<0, 1><<<dim3(MBV, 2, 1), 256, 0, stream>>>(src, nullptr, vp_w, nullptr, 0,
        vp_b, nullptr, Creg, 0, BS_, 256, 256, 256, 256, 0);
    // 6. sampling offsets + aw logits, merged (N=384, dual weights) -> fp32 D12
    gemm_t<0, 0><<<dim3(MB, 3, 1), 256, 0, stream>>>(Bq, nullptr, samp_off_w, aw_w, 256,
        samp_off_b, aw_b, D12, 0, NTOK_, 384, 256, 256, 384, 0);
    // 7. deformable sampling (bf16 value, bf16 out)
    deform_kernel<<<NTOK_ / 4, 256, 0, stream>>>((const ushort_t*)Creg, D12, refpts, (ushort_t*)E);
    // 8. output projection of cross-attn (A bf16), split-K x2: partial0=F, partial1=Bq (dead)
    gemm_t<2, 0><<<dim3(MB, 2, 2), 256, 0, stream>>>(E, nullptr, op_w, nullptr, 0,
        op_b, nullptr, F, (long long)(Bq - F), NTOK_, 256, 256, 128, 256, 0);
    // 9. LN2 (+ residual over 2 partials), in place on A
    ln_kernel<<<NTOK_, 256, 0, stream>>>(A, F, 2, (long long)(Bq - F),
                                         ln2_g, ln2_b, A, nullptr, nullptr);
    // 10. FFN1 + ReLU -> bf16 hidden [NTOK,1024]
    gemm_t<0, 1><<<dim3(MB, 8, 1), 256, 0, stream>>>(A, nullptr, ffn1_w, nullptr, 0,
        ffn1_b, nullptr, Creg, 0, NTOK_, DFF_, 256, 256, DFF_, 1);
    // 11. FFN2 (A bf16), split-K x zparts: partials at E + z*NC (E, F, F+NC, F+2NC)
    gemm_t<2, 0><<<dim3(MB, 2, zparts), 256, 0, stream>>>(Creg, nullptr, ffn2_w, nullptr, 0,
        ffn2_b, nullptr, E, NC, NTOK_, 256, 1024, 1024 / zparts, 256, 0);
    // 12. LN3 (+ residual over zparts partials) -> d_out
    ln_kernel<<<NTOK_, 256, 0, stream>>>(A, E, zparts, NC,
                                         ln3_g, ln3_b, (float*)d_out, nullptr, nullptr);
}

// Round 8
// 454.424 us; speedup vs baseline: 2.0012x; 1.0979x over previous
//
#include <hip/hip_runtime.h>
#include <cstddef>

// Problem constants (static per reference)
#define B_ 2
#define Q_ 300
#define T_ 25
#define C_ 256
#define NH_ 8
#define NL_ 4
#define NP_ 4
#define HD_ 32
#define DFF_ 1024
#define LQ_ (Q_ * T_)           // 7500
#define NTOK_ (B_ * LQ_)        // 15000
#define S_ 21760                // sum of level sizes
#define BS_ (B_ * S_)           // 43520

typedef __bf16 bf16x8 __attribute__((ext_vector_type(8)));
typedef float floatx4 __attribute__((ext_vector_type(4)));
typedef unsigned short ushort_t;

// round-half-up bf16 pack: lo16 = bf16(x), hi16 = bf16(y). Folds to v_perm.
__device__ __forceinline__ unsigned pack_bf16(float x, float y) {
    unsigned ux = __float_as_uint(x) + 0x8000u;
    unsigned uy = __float_as_uint(y) + 0x8000u;
    return (ux >> 16) | (uy & 0xFFFF0000u);
}
__device__ __forceinline__ ushort_t f2bf_s(float x) {
    return (ushort_t)((__float_as_uint(x) + 0x8000u) >> 16);
}
__device__ __forceinline__ float bf2f(ushort_t u) {
    return __uint_as_float((unsigned)u << 16);
}

// ---------------- bf16-MFMA GEMM, templated tile; 1-deep register prefetch; dual-W; split-K ----
// C[M,N] = act(A[M,K] @ W[N,K]^T + bias[N]); W rows >= N1 come from W2/bias2.
// AMODE: 0 = A fp32; 1 = A fp32 + A2 fp32 (sum); 2 = A bf16.
// OUT_BF16: C stored bf16 (no split-K) vs fp32 (split-K partial z -> C + z*partStride).
// GBMT: M-tile (64 or 128). N-tile fixed 128. 256 threads, 4 waves in 2x2;
// wave tile = (GBMT/2) x 64.  NOTE: 2-deep prefetch spills (R6) — keep 1-deep.
#define GBN 128
#define GBK 32
#define LDA_S 40   // LDS row stride in bf16 (pad 32 -> 40 to break bank stride)

template<int AMODE, int OUT_BF16, int GBMT>
__global__ __launch_bounds__(256) void gemm_t(
    const void* __restrict__ Av, const float* __restrict__ A2,
    const float* __restrict__ W, const float* __restrict__ W2, int N1,
    const float* __restrict__ bias, const float* __restrict__ bias2,
    void* __restrict__ Cv, long long partStride,
    int M, int N, int K, int kChunk, int ldc, int relu)
{
    constexpr int LA = GBMT / 32;   // per-thread A load chunks
    constexpr int WM = GBMT / 2;    // wave tile rows
    constexpr int NI = WM / 16;     // A frags per wave

    __shared__ unsigned short Asl[GBMT * LDA_S];
    __shared__ unsigned short Bsl[GBN * LDA_S];

    const int m0 = blockIdx.x * GBMT;
    const int n0 = blockIdx.y * GBN;
    const int z  = blockIdx.z;
    const int kbeg = z * kChunk;
    const int kend = min(K, kbeg + kChunk);

    const int t  = threadIdx.x;
    const int wid  = t >> 6;
    const int lane = t & 63;
    const int wm = (wid >> 1) * WM;    // wave tile origin in M
    const int wn = (wid & 1) * 64;     // wave tile origin in N
    const int fm = lane & 15;          // fragment row
    const int fq = (lane >> 4) * 8;    // fragment k-offset

    floatx4 acc[NI][4];
    #pragma unroll
    for (int i = 0; i < NI; ++i)
        #pragma unroll
        for (int j = 0; j < 4; ++j)
            acc[i][j] = (floatx4){0.f, 0.f, 0.f, 0.f};

    float4 pa[LA];   // fp32-A prefetch (AMODE 0/1)
    uint2  pab[LA];  // bf16-A prefetch (AMODE 2)
    float4 pw[4];
    const float* Af = (const float*)Av;
    const ushort_t* Ab = (const ushort_t*)Av;

    auto load_tiles = [&](int k0) {
        #pragma unroll
        for (int i = 0; i < LA; ++i) {
            int idx = t + 256 * i;
            int row = idx >> 3;
            int c4  = (idx & 7) * 4;
            int gm = m0 + row;
            if constexpr (AMODE == 2) {
                uint2 v = {0u, 0u};
                if (gm < M) v = *(const uint2*)(Ab + (size_t)gm * K + k0 + c4);
                pab[i] = v;
            } else {
                float4 v = make_float4(0.f, 0.f, 0.f, 0.f);
                if (gm < M) {
                    v = *(const float4*)(Af + (size_t)gm * K + k0 + c4);
                    if constexpr (AMODE == 1) {
                        float4 v2 = *(const float4*)(A2 + (size_t)gm * K + k0 + c4);
                        v.x += v2.x; v.y += v2.y; v.z += v2.z; v.w += v2.w;
                    }
                }
                pa[i] = v;
            }
        }
        #pragma unroll
        for (int i = 0; i < 4; ++i) {
            int idx = t + 256 * i;
            int row = idx >> 3;
            int c4  = (idx & 7) * 4;
            int gn = n0 + row;
            const float* wr;
            if (W2 && gn >= N1) wr = W2 + (size_t)(gn - N1) * K;
            else                wr = W + (size_t)gn * K;
            pw[i] = *(const float4*)(wr + k0 + c4);
        }
    };

    load_tiles(kbeg);
    for (int k0 = kbeg; k0 < kend; k0 += GBK) {
        // commit prefetched tile to LDS
        #pragma unroll
        for (int i = 0; i < LA; ++i) {
            int idx = t + 256 * i;
            int row = idx >> 3;
            int c4  = (idx & 7) * 4;
            if constexpr (AMODE == 2) {
                *(uint2*)&Asl[row * LDA_S + c4] = pab[i];
            } else {
                uint2 p;
                p.x = pack_bf16(pa[i].x, pa[i].y);
                p.y = pack_bf16(pa[i].z, pa[i].w);
                *(uint2*)&Asl[row * LDA_S + c4] = p;
            }
        }
        #pragma unroll
        for (int i = 0; i < 4; ++i) {
            int idx = t + 256 * i;
            int row = idx >> 3;
            int c4  = (idx & 7) * 4;
            uint2 q;
            q.x = pack_bf16(pw[i].x, pw[i].y);
            q.y = pack_bf16(pw[i].z, pw[i].w);
            *(uint2*)&Bsl[row * LDA_S + c4] = q;
        }
        __syncthreads();

        // issue next tile's global loads; they complete during the MFMAs below
        if (k0 + GBK < kend) load_tiles(k0 + GBK);

        bf16x8 af[NI], bfr[4];
        #pragma unroll
        for (int i = 0; i < NI; ++i)
            af[i] = *(const bf16x8*)&Asl[(wm + i * 16 + fm) * LDA_S + fq];
        #pragma unroll
        for (int j = 0; j < 4; ++j)
            bfr[j] = *(const bf16x8*)&Bsl[(wn + j * 16 + fm) * LDA_S + fq];

        #pragma unroll
        for (int i = 0; i < NI; ++i)
            #pragma unroll
            for (int j = 0; j < 4; ++j)
                acc[i][j] = __builtin_amdgcn_mfma_f32_16x16x32_bf16(af[i], bfr[j], acc[i][j], 0, 0, 0);
        __syncthreads();
    }

    // epilogue: C/D layout col=lane&15, row=(lane>>4)*4+reg
    float* Cf = (float*)Cv + (long long)z * partStride;
    ushort_t* Cb = (ushort_t*)Cv;
    const int cr = (lane >> 4) * 4;
    const int cc = lane & 15;
    #pragma unroll
    for (int j = 0; j < 4; ++j) {
        int gn = n0 + wn + j * 16 + cc;
        float bia = 0.f;
        if (z == 0) bia = (bias2 && gn >= N1) ? bias2[gn - N1] : bias[gn];
        #pragma unroll
        for (int i = 0; i < NI; ++i) {
            #pragma unroll
            for (int r = 0; r < 4; ++r) {
                int gm = m0 + wm + i * 16 + cr + r;
                if (gm < M) {
                    float v = acc[i][j][r] + bia;
                    if (relu) v = fmaxf(v, 0.f);
                    if constexpr (OUT_BF16) Cb[(size_t)gm * ldc + gn] = f2bf_s(v);
                    else                    Cf[(size_t)gm * ldc + gn] = v;
                }
            }
        }
    }
}

// ---------------- self-attention over T=25, one wave per (seq, head); bf16 in/out ----------------
__global__ __launch_bounds__(64) void attn_kernel(
    const ushort_t* __restrict__ qkv,   // [NTOK, 768] bf16: q|k|v per token
    ushort_t* __restrict__ o)           // [NTOK, 256] bf16
{
    int sh = blockIdx.x;
    int s = sh >> 3, h = sh & 7;     // s in [0, 600), h in [0, 8)
    __shared__ float qs[T_][HD_], ks[T_][HD_], vs[T_][HD_];
    int t = threadIdx.x;

    for (int idx = t; idx < T_ * HD_; idx += 64) {
        int i = idx >> 5, d = idx & 31;
        size_t base = ((size_t)(s * T_ + i)) * 768 + h * HD_ + d;
        qs[i][d] = bf2f(qkv[base]);
        ks[i][d] = bf2f(qkv[base + 256]);
        vs[i][d] = bf2f(qkv[base + 512]);
    }
    __syncthreads();

    if (t < T_) {
        float sc[T_];
        float mx = -1e30f;
        #pragma unroll
        for (int j = 0; j < T_; ++j) {
            float dot = 0.f;
            #pragma unroll
            for (int d = 0; d < HD_; ++d) dot += qs[t][d] * ks[j][d];
            sc[j] = dot * 0.17677669529663687f;  // 1/sqrt(32)
            mx = fmaxf(mx, sc[j]);
        }
        float sum = 0.f;
        #pragma unroll
        for (int j = 0; j < T_; ++j) { sc[j] = __expf(sc[j] - mx); sum += sc[j]; }
        float inv = 1.f / sum;
        float out[HD_];
        #pragma unroll
        for (int d = 0; d < HD_; ++d) out[d] = 0.f;
        for (int j = 0; j < T_; ++j) {
            float p = sc[j] * inv;
            #pragma unroll
            for (int d = 0; d < HD_; ++d) out[d] += p * vs[j][d];
        }
        size_t ob = ((size_t)(s * T_ + t)) * C_ + h * HD_;
        #pragma unroll
        for (int d = 0; d < HD_; ++d) o[ob + d] = f2bf_s(out[d]);
    }
}

// ---------------- fused residual + LayerNorm; r = sum of nparts fp32 partials ----------------
__global__ __launch_bounds__(256) void ln_kernel(
    const float* __restrict__ x, const float* __restrict__ r,
    int nparts, long long rstride,
    const float* __restrict__ g, const float* __restrict__ b,
    float* __restrict__ out, const float* __restrict__ pos,
    float* __restrict__ qout)
{
    int tok = blockIdx.x;
    int t = threadIdx.x;
    size_t base = (size_t)tok * C_;
    float v = x[base + t];
    for (int p = 0; p < nparts; ++p)
        v += r[(long long)base + t + (long long)p * rstride];

    float s = v, ss = v * v;
    #pragma unroll
    for (int off = 32; off; off >>= 1) {
        s += __shfl_down(s, off);
        ss += __shfl_down(ss, off);
    }
    __shared__ float ws[4], wss[4];
    __shared__ float mean_s, rstd_s;
    int wid = t >> 6, lane = t & 63;
    if (lane == 0) { ws[wid] = s; wss[wid] = ss; }
    __syncthreads();
    if (t == 0) {
        float S = 0.f, SS = 0.f;
        #pragma unroll
        for (int i = 0; i < 4; ++i) { S += ws[i]; SS += wss[i]; }
        float m = S / 256.f;
        float var = SS / 256.f - m * m;
        mean_s = m;
        rstd_s = rsqrtf(var + 1e-5f);
    }
    __syncthreads();
    float y = (v - mean_s) * rstd_s * g[t] + b[t];
    out[base + t] = y;
    if (qout) qout[base + t] = y + pos[base + t];
}

// ---------------- deformable sampling: 2 tokens/wave, 4 lanes per head (uint4=8 bf16) ----------
__global__ __launch_bounds__(256) void deform_kernel(
    const ushort_t* __restrict__ value,   // [B, S, NH, HD] bf16
    const float* __restrict__ d12,        // [NTOK, 384] = offsets | aw logits
    const float* __restrict__ refpts,     // [B, LQ, NL, 2]
    ushort_t* __restrict__ out)           // [NTOK, 256] bf16, laid out (tok, h, d)
{
    const int lane = threadIdx.x & 63;
    const int wave = threadIdx.x >> 6;
    const int half = lane >> 5;                    // token slot within wave
    const int tok = blockIdx.x * 8 + wave * 2 + half;
    const int h  = (lane >> 2) & 7;                // head 0..7
    const int d8 = (lane & 3) * 8;                 // channel offset 0,8,16,24
    const int b = tok / LQ_;

    // softmax over 16 attention-weight logits (replicated across 4 lanes of a head)
    const float* awp = d12 + (size_t)tok * 384 + 256 + h * 16;
    float logit[16];
    float mx = -1e30f;
    #pragma unroll
    for (int i = 0; i < 16; ++i) { logit[i] = awp[i]; mx = fmaxf(mx, logit[i]); }
    float sum = 0.f;
    #pragma unroll
    for (int i = 0; i < 16; ++i) { logit[i] = __expf(logit[i] - mx); sum += logit[i]; }
    float inv = 1.f / sum;

    const float* offp = d12 + (size_t)tok * 384 + h * 32;
    const float* refp = refpts + (size_t)tok * (NL_ * 2);

    const int HW[4]     = {128, 64, 32, 16};
    const int starts[4] = {0, 16384, 20480, 21504};

    float accv[8];
    #pragma unroll
    for (int i = 0; i < 8; ++i) accv[i] = 0.f;

    #pragma unroll
    for (int l = 0; l < 4; ++l) {
        const int Hl = HW[l], Wl = HW[l];
        float rx = refp[l * 2 + 0], ry = refp[l * 2 + 1];
        const ushort_t* vbase = value + ((size_t)b * S_ + starts[l]) * (NH_ * HD_) + h * HD_ + d8;
        #pragma unroll
        for (int p = 0; p < 4; ++p) {
            float ox = offp[(l * 4 + p) * 2 + 0];
            float oy = offp[(l * 4 + p) * 2 + 1];
            float xl = rx * (float)Wl + ox - 0.5f;
            float yl = ry * (float)Hl + oy - 0.5f;
            float x0f = floorf(xl), y0f = floorf(yl);
            int x0 = (int)x0f, y0 = (int)y0f;
            float wx1 = xl - x0f, wy1 = yl - y0f;
            float wx0 = 1.f - wx1, wy0 = 1.f - wy1;
            float aww = logit[l * 4 + p] * inv;

            #pragma unroll
            for (int c = 0; c < 4; ++c) {
                int dx = c & 1, dy = c >> 1;
                int xi = x0 + dx, yi = y0 + dy;
                float w = (dx ? wx1 : wx0) * (dy ? wy1 : wy0);
                bool valid = (xi >= 0) & (xi < Wl) & (yi >= 0) & (yi < Hl);
                int xc = min(max(xi, 0), Wl - 1);
                int yc = min(max(yi, 0), Hl - 1);
                float wc = (valid ? w : 0.f) * aww;
                uint4 raw = *(const uint4*)(vbase + ((size_t)(yc * Wl + xc)) * (NH_ * HD_));
                accv[0] += __uint_as_float((raw.x & 0xFFFFu) << 16) * wc;
                accv[1] += __uint_as_float(raw.x & 0xFFFF0000u) * wc;
                accv[2] += __uint_as_float((raw.y & 0xFFFFu) << 16) * wc;
                accv[3] += __uint_as_float(raw.y & 0xFFFF0000u) * wc;
                accv[4] += __uint_as_float((raw.z & 0xFFFFu) << 16) * wc;
                accv[5] += __uint_as_float(raw.z & 0xFFFF0000u) * wc;
                accv[6] += __uint_as_float((raw.w & 0xFFFFu) << 16) * wc;
                accv[7] += __uint_as_float(raw.w & 0xFFFF0000u) * wc;
            }
        }
    }
    uint4 po;
    po.x = pack_bf16(accv[0], accv[1]);
    po.y = pack_bf16(accv[2], accv[3]);
    po.z = pack_bf16(accv[4], accv[5]);
    po.w = pack_bf16(accv[6], accv[7]);
    *(uint4*)(out + (size_t)tok * C_ + h * HD_ + d8) = po;
}

// ---------------- host launch ----------------
extern "C" void kernel_launch(void* const* d_in, const int* in_sizes, int n_in,
                              void* d_out, int out_size, void* d_ws, size_t ws_size,
                              hipStream_t stream) {
    const float* tgt_text = (const float*)d_in[0];
    const float* pos      = (const float*)d_in[1];
    const float* refpts   = (const float*)d_in[2];
    const float* src      = (const float*)d_in[3];
    // d_in[4], d_in[5]: spatial shapes / level starts (static, unused)
    const float* in_proj_w  = (const float*)d_in[6];
    const float* in_proj_b  = (const float*)d_in[7];
    const float* out_proj_w = (const float*)d_in[8];
    const float* out_proj_b = (const float*)d_in[9];
    const float* ln1_g = (const float*)d_in[10];
    const float* ln1_b = (const float*)d_in[11];
    const float* samp_off_w = (const float*)d_in[12];
    const float* samp_off_b = (const float*)d_in[13];
    const float* aw_w = (const float*)d_in[14];
    const float* aw_b = (const float*)d_in[15];
    const float* vp_w = (const float*)d_in[16];
    const float* vp_b = (const float*)d_in[17];
    const float* op_w = (const float*)d_in[18];
    const float* op_b = (const float*)d_in[19];
    const float* ln2_g = (const float*)d_in[20];
    const float* ln2_b = (const float*)d_in[21];
    const float* ffn1_w = (const float*)d_in[22];
    const float* ffn1_b = (const float*)d_in[23];
    const float* ffn2_w = (const float*)d_in[24];
    const float* ffn2_b = (const float*)d_in[25];
    const float* ln3_g = (const float*)d_in[26];
    const float* ln3_b = (const float*)d_in[27];

    const long long NC = (long long)NTOK_ * C_;    // 3,840,000 floats
    float* ws = (float*)d_ws;
    float* A    = ws;                               // [NTOK,C] fp32  tgt (post-LN1/LN2)
    float* Bq   = ws + NC;                          // [NTOK,C] fp32  query
    float* Creg = ws + 2 * NC;                      // region: qkv/value/ffn-hidden (bf16)
    float* D12  = Creg + (long long)NTOK_ * DFF_;   // [NTOK,384] fp32 offsets|aw
    float* E    = D12 + (long long)NTOK_ * 384;     // [NTOK,C]: bf16 attn/deform out; fp32 FFN2 partial0
    float* F    = E + NC;                           // [NTOK,C] fp32 proj results / FFN2 partial1

    const int MB64  = (NTOK_ + 63) / 64;    // 235
    const int MB128 = (NTOK_ + 127) / 128;  // 118
    const int MBV64 = BS_ / 64;             // 680

    // 1. QK projection on (tgt+pos) -> qkv bf16 cols 0..511; V projection -> cols 512..767
    gemm_t<1, 1, 64><<<dim3(MB64, 4, 1), 256, 0, stream>>>(tgt_text, pos, in_proj_w, nullptr, 0,
        in_proj_b, nullptr, Creg, 0, NTOK_, 512, 256, 256, 768, 0);
    gemm_t<0, 1, 64><<<dim3(MB64, 2, 1), 256, 0, stream>>>(tgt_text, nullptr, in_proj_w + 512 * 256, nullptr, 0,
        in_proj_b + 512, nullptr, (void*)((ushort_t*)Creg + 512), 0, NTOK_, 256, 256, 256, 768, 0);
    // 2. self-attention (bf16 -> bf16)
    attn_kernel<<<B_ * Q_ * NH_, 64, 0, stream>>>((const ushort_t*)Creg, (ushort_t*)E);
    // 3. out projection (A bf16), 64-tile, no split-K -> F fp32
    gemm_t<2, 0, 64><<<dim3(MB64, 2, 1), 256, 0, stream>>>(E, nullptr, out_proj_w, nullptr, 0,
        out_proj_b, nullptr, F, 0, NTOK_, 256, 256, 256, 256, 0);
    // 4. LN1 (+ residual), and query = tgt + pos
    ln_kernel<<<NTOK_, 256, 0, stream>>>(tgt_text, F, 1, 0,
                                         ln1_g, ln1_b, A, pos, Bq);
    // 5. value projection -> bf16 [BS,256]
    gemm_t<0, 1, 64><<<dim3(MBV64, 2, 1), 256, 0, stream>>>(src, nullptr, vp_w, nullptr, 0,
        vp_b, nullptr, Creg, 0, BS_, 256, 256, 256, 256, 0);
    // 6. sampling offsets + aw logits, merged (N=384, dual weights) -> fp32 D12
    gemm_t<0, 0, 64><<<dim3(MB64, 3, 1), 256, 0, stream>>>(Bq, nullptr, samp_off_w, aw_w, 256,
        samp_off_b, aw_b, D12, 0, NTOK_, 384, 256, 256, 384, 0);
    // 7. deformable sampling (bf16 value, bf16 out); 2 tokens per wave
    deform_kernel<<<NTOK_ / 8, 256, 0, stream>>>((const ushort_t*)Creg, D12, refpts, (ushort_t*)E);
    // 8. output projection of cross-attn (A bf16), 64-tile, no split-K -> F fp32
    gemm_t<2, 0, 64><<<dim3(MB64, 2, 1), 256, 0, stream>>>(E, nullptr, op_w, nullptr, 0,
        op_b, nullptr, F, 0, NTOK_, 256, 256, 256, 256, 0);
    // 9. LN2 (+ residual), in place on A
    ln_kernel<<<NTOK_, 256, 0, stream>>>(A, F, 1, 0,
                                         ln2_g, ln2_b, A, nullptr, nullptr);
    // 10. FFN1 + ReLU -> bf16 hidden [NTOK,1024]; 128-tile (944 blocks)
    gemm_t<0, 1, 128><<<dim3(MB128, 8, 1), 256, 0, stream>>>(A, nullptr, ffn1_w, nullptr, 0,
        ffn1_b, nullptr, Creg, 0, NTOK_, DFF_, 256, 256, DFF_, 1);
    // 11. FFN2 (A bf16), 64-tile + split-K x2: partial0=E, partial1=F (=E+NC)
    gemm_t<2, 0, 64><<<dim3(MB64, 2, 2), 256, 0, stream>>>(Creg, nullptr, ffn2_w, nullptr, 0,
        ffn2_b, nullptr, E, NC, NTOK_, 256, 1024, 512, 256, 0);
    // 12. LN3 (+ residual over 2 partials) -> d_out
    ln_kernel<<<NTOK_, 256, 0, stream>>>(A, E, 2, NC,
                                         ln3_g, ln3_b, (float*)d_out, nullptr, nullptr);
}